// Round 4
// baseline (792.890 us; speedup 1.0000x reference)
//
#include <hip/hip_runtime.h>

// Problem constants (match reference setup_inputs / module constants)
#define EPS_F      1e-4f
#define GRID_RES_F 0.01f
#define ATOL_F     0.01f
#define RTOL_F     1e-5f

static constexpr int V = 1200;
static constexpr int E = 4800;
static constexpr int S = V + E;      // 6000 filtration points
static constexpr int P = 2500;
static constexpr int R = 3;
static constexpr int NROW = 2 * R;   // (bar-set, r) rows per sample point

typedef float vfloat4 __attribute__((ext_vector_type(4)));  // native vec for NT store

// Output layout (flat fp32, return order):
//   bars0: [0, 7500)   bars1: [7500, 15000)
//   G0: (R,P,2S) at 15000   G1: follows   Gc0: (R,P,2)   Gc1: follows
static constexpr size_t G0_BASE  = 15000ull;
static constexpr size_t G_ELEMS  = (size_t)R * P * 2 * S;   // 90,000,000
static constexpr size_t GC0_BASE = G0_BASE + 2 * G_ELEMS;   // 180,015,000

// ---------------------------------------------------------------------------
// Kernel 1: build filtration table. filt[j] = (fx, fy, tol_x, tol_y)
// ---------------------------------------------------------------------------
__global__ void build_filt_kernel(const float* __restrict__ f_v,
                                  const int*   __restrict__ edges,
                                  float4*      __restrict__ filt) {
    int j = blockIdx.x * blockDim.x + threadIdx.x;
    if (j >= S) return;
    float fx, fy;
    if (j < V) {
        fx = f_v[2 * j];
        fy = f_v[2 * j + 1];
    } else {
        int e = j - V;
        int a = edges[2 * e];
        int b = edges[2 * e + 1];
        fx = __fadd_rn(fmaxf(f_v[2 * a],     f_v[2 * b]),     EPS_F);
        fy = __fadd_rn(fmaxf(f_v[2 * a + 1], f_v[2 * b + 1]), EPS_F);
    }
    // tol = ATOL + RTOL*|f| with NumPy per-op rounding (no fma contraction).
    float tolx = __fadd_rn(ATOL_F, __fmul_rn(RTOL_F, fabsf(fx)));
    float toly = __fadd_rn(ATOL_F, __fmul_rn(RTOL_F, fabsf(fy)));
    filt[j] = make_float4(fx, fy, tolx, toly);
}

// ---------------------------------------------------------------------------
// min_k |l[k] - f| ; comparing this to tol is bit-exact-equivalent to
// any_k(|l[k]-f| <= tol) — min/cmp involve no rounding. Subs keep ref rounding.
// ---------------------------------------------------------------------------
__device__ __forceinline__ float mindist(const float* l, float f) {
    float a = fabsf(__fsub_rn(l[0], f));
    float b = fabsf(__fsub_rn(l[1], f));
    float c = fabsf(__fsub_rn(l[2], f));
    float d = fabsf(__fsub_rn(l[3], f));
    float e = fabsf(__fsub_rn(l[4], f));
    return fminf(fminf(fminf(a, b), fminf(c, d)), e);  // -> v_min3 pairs
}

__device__ __forceinline__ void cellrow(const float4& f, float sg, bool ab, bool be,
                                        const float* lxq, const float* lyq, int q,
                                        float& vx, float& vy,
                                        unsigned& fUx, unsigned& fLx,
                                        unsigned& fUy, unsigned& fLy) {
    bool cx = (mindist(lxq, f.x) <= f.z) && (f.y <= lyq[4]);
    bool cy = (mindist(lyq, f.y) <= f.w) && (f.x <= lxq[4]);
    vx = cx ? sg : 0.0f;   // vx = ux - lx == condx ? (above - below) : 0
    vy = cy ? sg : 0.0f;
    if (cx && ab) fUx |= 1u << q;
    if (cx && be) fLx |= 1u << q;
    if (cy && ab) fUy |= 1u << q;
    if (cy && be) fLy |= 1u << q;
}

// ---------------------------------------------------------------------------
// Kernel 2: one block per sample point p; handles all 6 (bar-set, r) rows so
// each filt cell is loaded once and reused 6x.
// ---------------------------------------------------------------------------
__global__ __launch_bounds__(256) void grad_kernel(
        const float4* __restrict__ filt,
        const float*  __restrict__ bars0,
        const float*  __restrict__ bars1,
        const float*  __restrict__ sample_pts,
        float*        __restrict__ d_out) {
    const int p = blockIdx.x;   // 0..P-1

    const float px = sample_pts[2 * p];
    const float py = sample_pts[2 * p + 1];
    const float psum = __fadd_rn(px, py);

    // Per-row line positions (shift in {-2..2}); shift*s is exact for these
    // shifts, so only the adds need pinned rounding. Kept in registers.
    float lx[NROW][5], ly[NROW][5];
#pragma unroll
    for (int q = 0; q < NROW; ++q) {
        const int b = q / R, r = q % R;
        const float* bar = b ? bars1 : bars0;
        float s  = __fadd_rn(bar[p * R + r], GRID_RES_F);
        float s2 = __fmul_rn(2.0f, s);    // exact (power of 2)
        lx[q][0] = __fadd_rn(-s2, px); lx[q][1] = __fadd_rn(-s, px);
        lx[q][2] = px;
        lx[q][3] = __fadd_rn( s, px);  lx[q][4] = __fadd_rn(s2, px);
        ly[q][0] = __fadd_rn(-s2, py); ly[q][1] = __fadd_rn(-s, py);
        ly[q][2] = py;
        ly[q][3] = __fadd_rn( s, py);  ly[q][4] = __fadd_rn(s2, py);
    }

    float* grow[NROW];
#pragma unroll
    for (int q = 0; q < NROW; ++q) {
        const int b = q / R, r = q % R;
        grow[q] = d_out + G0_BASE + (size_t)b * G_ELEMS
                        + ((size_t)(r * P + p)) * (2 * S);
    }

    unsigned fUx = 0, fLx = 0, fUy = 0, fLy = 0;

    // Each thread: 2 adjacent cells per iteration -> one float4 store per row.
    for (int j0 = threadIdx.x * 2; j0 < S; j0 += 512) {
        float4 f0 = filt[j0];
        float4 f1 = filt[j0 + 1];
        float fs0 = __fadd_rn(f0.x, f0.y);
        float fs1 = __fadd_rn(f1.x, f1.y);
        bool ab0 = fs0 > psum, be0 = fs0 < psum;
        bool ab1 = fs1 > psum, be1 = fs1 < psum;
        float sg0 = ab0 ? 1.0f : (be0 ? -1.0f : 0.0f);
        float sg1 = ab1 ? 1.0f : (be1 ? -1.0f : 0.0f);
#pragma unroll
        for (int q = 0; q < NROW; ++q) {
            float o0, o1, o2, o3;
            cellrow(f0, sg0, ab0, be0, lx[q], ly[q], q, o0, o1,
                    fUx, fLx, fUy, fLy);
            cellrow(f1, sg1, ab1, be1, lx[q], ly[q], q, o2, o3,
                    fUx, fLx, fUy, fLy);
            vfloat4 o = {o0, o1, o2, o3};
            // Write-once stream: nontemporal to keep filt resident in L2.
            __builtin_nontemporal_store(o,
                reinterpret_cast<vfloat4*>(grow[q] + 2 * j0));
        }
    }

    // Row-wide any() flags: benign-race LDS stores (all writers store 1).
    __shared__ int shf[NROW * 4];
    if (threadIdx.x < NROW * 4) shf[threadIdx.x] = 0;
    __syncthreads();
#pragma unroll
    for (int q = 0; q < NROW; ++q) {
        if ((fUx >> q) & 1) shf[q * 4 + 0] = 1;
        if ((fLx >> q) & 1) shf[q * 4 + 1] = 1;
        if ((fUy >> q) & 1) shf[q * 4 + 2] = 1;
        if ((fLy >> q) & 1) shf[q * 4 + 3] = 1;
    }
    __syncthreads();

    if (threadIdx.x < NROW) {
        const int q = threadIdx.x, b = q / R, r = q % R;
        float cx = shf[q * 4 + 0] ? -1.0f : (shf[q * 4 + 1] ? 1.0f : 0.0f);
        float cy = shf[q * 4 + 2] ? -1.0f : (shf[q * 4 + 3] ? 1.0f : 0.0f);
        size_t gc = GC0_BASE + (size_t)b * ((size_t)R * P * 2)
                             + ((size_t)(r * P + p)) * 2;
        d_out[gc]     = cx;
        d_out[gc + 1] = cy;
    }
}

// ---------------------------------------------------------------------------
extern "C" void kernel_launch(void* const* d_in, const int* in_sizes, int n_in,
                              void* d_out, int out_size, void* d_ws, size_t ws_size,
                              hipStream_t stream) {
    const float* f_v        = (const float*)d_in[0];
    const int*   edges      = (const int*)d_in[1];
    const float* bars0      = (const float*)d_in[2];
    const float* bars1      = (const float*)d_in[3];
    const float* sample_pts = (const float*)d_in[4];
    float* out = (float*)d_out;

    float4* filt = (float4*)d_ws;   // S * 16 B = 96 KB scratch

    // bars0 / bars1 pass through to output.
    (void)hipMemcpyAsync(out,         bars0, (size_t)P * R * sizeof(float),
                         hipMemcpyDeviceToDevice, stream);
    (void)hipMemcpyAsync(out + P * R, bars1, (size_t)P * R * sizeof(float),
                         hipMemcpyDeviceToDevice, stream);

    build_filt_kernel<<<(S + 255) / 256, 256, 0, stream>>>(f_v, edges, filt);

    grad_kernel<<<P, 256, 0, stream>>>(filt, bars0, bars1, sample_pts, out);
}

// Round 5
// 726.721 us; speedup vs baseline: 1.0911x; 1.0911x over previous
//
#include <hip/hip_runtime.h>

// Problem constants (match reference setup_inputs / module constants)
#define EPS_F      1e-4f
#define GRID_RES_F 0.01f
#define ATOL_F     0.01f
#define RTOL_F     1e-5f

static constexpr int V = 1200;
static constexpr int E = 4800;
static constexpr int S = V + E;      // 6000 filtration points
static constexpr int P = 2500;
static constexpr int R = 3;

// Output layout (flat fp32, return order):
//   bars0: [0, 7500)   bars1: [7500, 15000)
//   G0: (R,P,2S) at 15000   G1: follows   Gc0: (R,P,2)   Gc1: follows
static constexpr size_t G0_BASE  = 15000ull;
static constexpr size_t G_ELEMS  = (size_t)R * P * 2 * S;   // 90,000,000
static constexpr size_t GC0_BASE = G0_BASE + 2 * G_ELEMS;   // 180,015,000

// ---------------------------------------------------------------------------
// Kernel 1: build filtration table. filt[j] = (fx, fy, tol_x, tol_y)
// ---------------------------------------------------------------------------
__global__ void build_filt_kernel(const float* __restrict__ f_v,
                                  const int*   __restrict__ edges,
                                  float4*      __restrict__ filt) {
    int j = blockIdx.x * blockDim.x + threadIdx.x;
    if (j >= S) return;
    float fx, fy;
    if (j < V) {
        fx = f_v[2 * j];
        fy = f_v[2 * j + 1];
    } else {
        int e = j - V;
        int a = edges[2 * e];
        int b = edges[2 * e + 1];
        fx = __fadd_rn(fmaxf(f_v[2 * a],     f_v[2 * b]),     EPS_F);
        fy = __fadd_rn(fmaxf(f_v[2 * a + 1], f_v[2 * b + 1]), EPS_F);
    }
    // tol = ATOL + RTOL*|f| with NumPy per-op rounding (no fma contraction).
    float tolx = __fadd_rn(ATOL_F, __fmul_rn(RTOL_F, fabsf(fx)));
    float toly = __fadd_rn(ATOL_F, __fmul_rn(RTOL_F, fabsf(fy)));
    filt[j] = make_float4(fx, fy, tolx, toly);
}

// ---------------------------------------------------------------------------
// min_k |l[k] - f| ; comparing vs tol is bit-exact-equivalent to
// any_k(|l[k]-f| <= tol) — min/cmp involve no rounding. Subs keep ref rounding.
// (Field-proven: absmax 0.0 in round 4.)
// ---------------------------------------------------------------------------
__device__ __forceinline__ float mindist(const float* l, float f) {
    float a = fabsf(__fsub_rn(l[0], f));
    float b = fabsf(__fsub_rn(l[1], f));
    float c = fabsf(__fsub_rn(l[2], f));
    float d = fabsf(__fsub_rn(l[3], f));
    float e = fabsf(__fsub_rn(l[4], f));
    return fminf(fminf(fminf(a, b), fminf(c, d)), e);  // -> v_min3 pairs
}

__device__ __forceinline__ void cell(const float4& f, float psum,
                                     const float* lxs, const float* lys,
                                     float& vx, float& vy,
                                     int& aux, int& alx, int& auy, int& aly) {
    float fsum = __fadd_rn(f.x, f.y);
    bool ab = fsum > psum, be = fsum < psum;
    float sg = ab ? 1.0f : (be ? -1.0f : 0.0f);
    bool cx = (mindist(lxs, f.x) <= f.z) && (f.y <= lys[4]);
    bool cy = (mindist(lys, f.y) <= f.w) && (f.x <= lxs[4]);
    vx = cx ? sg : 0.0f;   // vx = ux - lx == condx ? (above - below) : 0
    vy = cy ? sg : 0.0f;
    aux |= (int)(cx && ab); alx |= (int)(cx && be);
    auy |= (int)(cy && ab); aly |= (int)(cy && be);
}

// ---------------------------------------------------------------------------
// Kernel 2: one block per (bar-set, r, p) row — R1 structure (lean VGPR,
// 15000 blocks). New vs R1: 4 cells/thread/iter (2x float4 stores) with
// next-iteration filt loads prefetched before the current compute/store.
// ---------------------------------------------------------------------------
__global__ __launch_bounds__(256) void grad_kernel(
        const float4* __restrict__ filt,
        const float*  __restrict__ bars0,
        const float*  __restrict__ bars1,
        const float*  __restrict__ sample_pts,
        float*        __restrict__ d_out) {
    const int p = blockIdx.x;   // 0..P-1
    const int r = blockIdx.y;   // 0..R-1
    const int b = blockIdx.z;   // 0..1

    const float* bar = (b == 0) ? bars0 : bars1;
    const float px = sample_pts[2 * p];
    const float py = sample_pts[2 * p + 1];
    const float psum = __fadd_rn(px, py);
    const float s  = __fadd_rn(bar[p * R + r], GRID_RES_F);
    const float s2 = __fmul_rn(2.0f, s);   // exact (x2)

    float lxs[5], lys[5];
    lxs[0] = __fadd_rn(-s2, px); lxs[1] = __fadd_rn(-s, px); lxs[2] = px;
    lxs[3] = __fadd_rn( s, px);  lxs[4] = __fadd_rn(s2, px);
    lys[0] = __fadd_rn(-s2, py); lys[1] = __fadd_rn(-s, py); lys[2] = py;
    lys[3] = __fadd_rn( s, py);  lys[4] = __fadd_rn(s2, py);

    float* Grow = d_out + G0_BASE + (size_t)b * G_ELEMS
                        + ((size_t)(r * P + p)) * (2 * S);

    __shared__ int sh_flags[4];
    if (threadIdx.x < 4) sh_flags[threadIdx.x] = 0;
    __syncthreads();

    int aux = 0, alx = 0, auy = 0, aly = 0;

    // 4 cells per thread per iteration; stride 1024 cells per block sweep.
    int j = threadIdx.x * 4;
    float4 a0, a1, a2, a3;
    if (j < S) { a0 = filt[j]; a1 = filt[j+1]; a2 = filt[j+2]; a3 = filt[j+3]; }
    while (j < S) {
        const int jn = j + 1024;
        float4 b0, b1, b2, b3;
        if (jn < S) {  // prefetch next iteration's cells before compute/store
            b0 = filt[jn]; b1 = filt[jn+1]; b2 = filt[jn+2]; b3 = filt[jn+3];
        }
        float4 o0, o1;
        cell(a0, psum, lxs, lys, o0.x, o0.y, aux, alx, auy, aly);
        cell(a1, psum, lxs, lys, o0.z, o0.w, aux, alx, auy, aly);
        cell(a2, psum, lxs, lys, o1.x, o1.y, aux, alx, auy, aly);
        cell(a3, psum, lxs, lys, o1.z, o1.w, aux, alx, auy, aly);
        float4* dst = reinterpret_cast<float4*>(Grow + 2 * j);
        dst[0] = o0;
        dst[1] = o1;
        a0 = b0; a1 = b1; a2 = b2; a3 = b3;
        j = jn;
    }

    // Row-wide any() flags: benign-race shared writes (all writers store 1).
    if (aux) sh_flags[0] = 1;
    if (alx) sh_flags[1] = 1;
    if (auy) sh_flags[2] = 1;
    if (aly) sh_flags[3] = 1;
    __syncthreads();

    if (threadIdx.x == 0) {
        float cx = sh_flags[0] ? -1.0f : (sh_flags[1] ? 1.0f : 0.0f);
        float cy = sh_flags[2] ? -1.0f : (sh_flags[3] ? 1.0f : 0.0f);
        size_t gc = GC0_BASE + (size_t)b * ((size_t)R * P * 2)
                             + ((size_t)(r * P + p)) * 2;
        d_out[gc]     = cx;
        d_out[gc + 1] = cy;
    }
}

// ---------------------------------------------------------------------------
extern "C" void kernel_launch(void* const* d_in, const int* in_sizes, int n_in,
                              void* d_out, int out_size, void* d_ws, size_t ws_size,
                              hipStream_t stream) {
    const float* f_v        = (const float*)d_in[0];
    const int*   edges      = (const int*)d_in[1];
    const float* bars0      = (const float*)d_in[2];
    const float* bars1      = (const float*)d_in[3];
    const float* sample_pts = (const float*)d_in[4];
    float* out = (float*)d_out;

    float4* filt = (float4*)d_ws;   // S * 16 B = 96 KB scratch

    // bars0 / bars1 pass through to output.
    (void)hipMemcpyAsync(out,         bars0, (size_t)P * R * sizeof(float),
                         hipMemcpyDeviceToDevice, stream);
    (void)hipMemcpyAsync(out + P * R, bars1, (size_t)P * R * sizeof(float),
                         hipMemcpyDeviceToDevice, stream);

    build_filt_kernel<<<(S + 255) / 256, 256, 0, stream>>>(f_v, edges, filt);

    dim3 grid(P, R, 2);
    grad_kernel<<<grid, 256, 0, stream>>>(filt, bars0, bars1, sample_pts, out);
}